// Round 2
// baseline (7866.171 us; speedup 1.0000x reference)
//
#include <hip/hip_runtime.h>
#include <math.h>

#define DTOK 1222
#define NBOU 80
#define MM   160
#define FFD  2048
#define OQKV 3666

// ---------- reduction helpers (block = 256 threads = 4 waves) ----------
__device__ __forceinline__ float wave_red_sum(float v) {
#pragma unroll
  for (int off = 32; off; off >>= 1) v += __shfl_xor(v, off, 64);
  return v;
}

__device__ __forceinline__ float block_red_sum(float v, float* rb, int tid) {
  v = wave_red_sum(v);
  __syncthreads();                 // protect rb from any previous use
  if ((tid & 63) == 0) rb[tid >> 6] = v;
  __syncthreads();
  return rb[0] + rb[1] + rb[2] + rb[3];
}

// ---------- setup: pool L0 (NCHW) -> L1 (NHWC) ----------
__global__ __launch_bounds__(256) void k_pool0(const float* __restrict__ f,
                                               float* __restrict__ L1out) {
  int xc = blockIdx.x & 3, cc = blockIdx.x >> 2;   // 4 x-chunks, 16 c-chunks
  int y1 = blockIdx.y, b = blockIdx.z;
  int tid = threadIdx.x;
  __shared__ __align__(16) float tile[64][116];
  int c0 = cc * 64, x0 = xc * 56;
  const float* fb = f + (size_t)b * 1024 * 50176;
#pragma unroll
  for (int i = 0; i < 7; ++i) {
    int u = tid + 256 * i;            // 0..1791
    int q = u % 14;                   // float4 within 56-wide segment
    int seg = u / 14;                 // 0..127
    int c = seg >> 1, r = seg & 1;
    const float* src = fb + ((size_t)(c0 + c) * 224 + (2 * y1 + r)) * 224 + x0 + q * 4;
    float4 v = *(const float4*)src;
    *(float4*)&tile[c][r * 56 + q * 4] = v;
  }
  __syncthreads();
#pragma unroll
  for (int i = 0; i < 7; ++i) {
    int u = tid + 256 * i;            // 0..1791
    int xo = u >> 6;                  // 0..27
    int c = u & 63;
    float v = 0.25f * (tile[c][2 * xo] + tile[c][2 * xo + 1] +
                       tile[c][56 + 2 * xo] + tile[c][56 + 2 * xo + 1]);
    L1out[(((size_t)b * 112 + y1) * 112 + (x0 >> 1) + xo) * 1024 + c0 + c] = v;
  }
}

// ---------- setup: pool NHWC -> NHWC (2x2 mean) ----------
__global__ __launch_bounds__(256) void k_pool_nhwc(const float* __restrict__ in,
                                                   float* __restrict__ out, int Ho) {
  int x = blockIdx.x, y = blockIdx.y, b = blockIdx.z;
  int c = threadIdx.x * 4;
  int Hi = Ho * 2;
  const float* p00 = in + (((size_t)(b * Hi + 2 * y) * Hi) + 2 * x) * 1024 + c;
  const float* p01 = p00 + 1024;
  const float* p10 = p00 + (size_t)Hi * 1024;
  const float* p11 = p10 + 1024;
  float4 a = *(const float4*)p00, bv = *(const float4*)p01;
  float4 cv = *(const float4*)p10, dv = *(const float4*)p11;
  float4 r;
  r.x = 0.25f * (a.x + bv.x + cv.x + dv.x);
  r.y = 0.25f * (a.y + bv.y + cv.y + dv.y);
  r.z = 0.25f * (a.z + bv.z + cv.z + dv.z);
  r.w = 0.25f * (a.w + bv.w + cv.w + dv.w);
  *(float4*)(out + (((size_t)(b * Ho + y) * Ho) + x) * 1024 + c) = r;
}

// ---------- setup: positional encoding + boundary init ----------
__global__ __launch_bounds__(256) void k_pe(float* __restrict__ pe, int* __restrict__ bnd,
                                            const int* __restrict__ pb) {
  int n = blockIdx.x, tid = threadIdx.x;
  for (int d = tid; d < DTOK; d += 256) {
    int i = d >> 1;
    double e = exp((double)(2 * i) * (-log(10000.0) / (double)DTOK));
    double ang = (double)n * e;
    pe[n * DTOK + d] = (float)((d & 1) ? cos(ang) : sin(ang));
  }
  if (n == 0) {
    for (int t = tid; t < 2 * NBOU * 2; t += 256) bnd[t] = pb[t];  // full 320-int copy
  }
}

// ---------- per-iteration: gather + dots + tokens + LN + pe ----------
__global__ __launch_bounds__(256) void k_tok(const float* __restrict__ f,
                                             const float* __restrict__ L1,
                                             const float* __restrict__ L2,
                                             const float* __restrict__ L3,
                                             const int* __restrict__ bnd,
                                             const float* __restrict__ g,
                                             const float* __restrict__ bb,
                                             const float* __restrict__ pe,
                                             float* __restrict__ tok_out) {
  int blk = blockIdx.x;
  int b = blk / NBOU, n = blk % NBOU;
  int tid = threadIdx.x, wave = tid >> 6, lane = tid & 63;
  __shared__ __align__(16) float token[1224];
  __shared__ float red[4][52];
  __shared__ float rbuf[8];
  int bd0 = bnd[blk * 2 + 0], bd1 = bnd[blk * 2 + 1];

  // ---- scale 0: 49-lane window over NCHW; center tap is qf ----
  int oh = lane / 7 - 3, ow = lane % 7 - 3;
  int py = bd0 + oh, px = bd1 + ow;
  bool valid = (lane < 49) && (py >= 0) && (py < 224) && (px >= 0) && (px < 224);
  const float* fb = f + (size_t)b * 1024 * 50176;
  long sp = (long)py * 224 + px;
  float acc0 = 0.f;
  int c0 = wave * 256;
#pragma unroll 8
  for (int c = 0; c < 256; ++c) {
    int ch = c0 + c;
    float v = valid ? fb[(size_t)ch * 50176 + sp] : 0.f;
    float qc = __shfl(v, 24, 64);     // center (0,0) offset
    acc0 += qc * v;
    if (lane == 24) token[ch] = v;    // qf
  }
  if (lane < 49) red[wave][lane] = acc0;
  __syncthreads();
  if (tid < 49) token[1024 + tid] = red[0][tid] + red[1][tid] + red[2][tid] + red[3][tid];
  if (tid == 0) { token[1220] = (float)bd0; token[1221] = (float)bd1; }
  __syncthreads();

  // ---- scales 1..3: NHWC pyramid, wave-per-offset ----
#pragma unroll
  for (int s = 1; s <= 3; ++s) {
    const float* base = (s == 1) ? L1 : (s == 2) ? L2 : L3;
    int Hs = 224 >> s;
    int by = bd0 >> s, bx = bd1 >> s;
    const float* bp = base + (size_t)b * Hs * Hs * 1024;
    for (int o = wave; o < 49; o += 4) {
      int yy = by + o / 7 - 3, xx = bx + o % 7 - 3;
      float a = 0.f;
      if (yy >= 0 && yy < Hs && xx >= 0 && xx < Hs) {
        const float* kp = bp + ((size_t)yy * Hs + xx) * 1024;
#pragma unroll
        for (int j = 0; j < 4; ++j) {
          int c = (lane + 64 * j) * 4;
          float4 kv = *(const float4*)(kp + c);
          float4 qv = *(const float4*)(token + c);
          a += kv.x * qv.x + kv.y * qv.y + kv.z * qv.z + kv.w * qv.w;
        }
      }
      a = wave_red_sum(a);
      if (lane == 0) token[1024 + s * 49 + o] = a;
    }
  }
  __syncthreads();

  // ---- LayerNorm (two-pass) + pe, store ----
  float ls = 0.f;
  for (int d = tid; d < DTOK; d += 256) ls += token[d];
  float mean = block_red_sum(ls, rbuf, tid) * (1.0f / DTOK);
  float lq = 0.f;
  for (int d = tid; d < DTOK; d += 256) { float t = token[d] - mean; lq += t * t; }
  float var = block_red_sum(lq, rbuf, tid) * (1.0f / DTOK);
  float rstd = rsqrtf(var + 1e-5f);
  for (int d = tid; d < DTOK; d += 256) {
    float o = (token[d] - mean) * rstd * g[d] + bb[d] + pe[n * DTOK + d];
    tok_out[(size_t)blk * DTOK + d] = o;
  }
}

// ---------- generic fp32 GEMM: out[160,O] = A[160,K] @ W[O,K]^T + bias (+res)(relu) ----------
__global__ __launch_bounds__(256) void k_gemm(const float* __restrict__ A,
                                              const float* __restrict__ Wt,
                                              const float* __restrict__ bias,
                                              const float* __restrict__ res,
                                              float* __restrict__ out,
                                              int K, int O, int relu) {
  __shared__ __align__(16) float At[32][68];
  __shared__ __align__(16) float Bt[32][68];
  int tid = threadIdx.x;
  int o0 = blockIdx.x * 64, m0 = blockIdx.y * 64;
  int kk = tid & 31, rr = tid >> 5;
  int tm = tid & 15, to = tid >> 4;
  float acc[4][4] = {};
  for (int k0 = 0; k0 < K; k0 += 32) {
    bool kval = (k0 + kk) < K;
#pragma unroll
    for (int i = 0; i < 8; ++i) {
      int row = rr + 8 * i;
      int m = m0 + row;
      At[kk][row] = (kval && m < MM) ? A[(size_t)m * K + k0 + kk] : 0.f;
      int o = o0 + row;
      Bt[kk][row] = (kval && o < O) ? Wt[(size_t)o * K + k0 + kk] : 0.f;
    }
    __syncthreads();
#pragma unroll
    for (int q = 0; q < 32; ++q) {
      float4 av = *(const float4*)&At[q][tm * 4];
      float4 bv = *(const float4*)&Bt[q][to * 4];
      float a4[4] = {av.x, av.y, av.z, av.w};
      float b4[4] = {bv.x, bv.y, bv.z, bv.w};
#pragma unroll
      for (int im = 0; im < 4; ++im)
#pragma unroll
        for (int io = 0; io < 4; ++io) acc[im][io] += a4[im] * b4[io];
    }
    __syncthreads();
  }
#pragma unroll
  for (int im = 0; im < 4; ++im) {
    int m = m0 + tm * 4 + im;
    if (m >= MM) continue;
#pragma unroll
    for (int io = 0; io < 4; ++io) {
      int o = o0 + to * 4 + io;
      if (o < O) {
        float v = acc[im][io] + bias[o];
        if (relu) v = fmaxf(v, 0.f);
        if (res) v += res[(size_t)m * O + o];
        out[(size_t)m * O + o] = v;
      }
    }
  }
}

// ---------- attention (per (b,n) row) ----------
__global__ __launch_bounds__(256) void k_attn(const float* __restrict__ qkv,
                                              float* __restrict__ attn_out) {
  int blk = blockIdx.x;
  int b = blk / NBOU;
  int tid = threadIdx.x, wave = tid >> 6, lane = tid & 63;
  __shared__ float p[80];
  float qr[20];
  const float* qrow = qkv + (size_t)blk * OQKV;
#pragma unroll
  for (int j = 0; j < 20; ++j) {
    int d = lane + 64 * j;
    qr[j] = (d < DTOK) ? qrow[d] : 0.f;
  }
  for (int m2 = wave; m2 < 80; m2 += 4) {
    const float* krow = qkv + (size_t)(b * NBOU + m2) * OQKV + DTOK;
    float a = 0.f;
#pragma unroll
    for (int j = 0; j < 20; ++j) {
      int d = lane + 64 * j;
      if (d < DTOK) a += qr[j] * krow[d];
    }
    a = wave_red_sum(a);
    if (lane == 0) p[m2] = a * (1.0f / 34.957116f);  // 1/sqrt(1222)
  }
  __syncthreads();
  if (wave == 0) {
    float x0 = p[lane];
    float x1 = (lane < 16) ? p[64 + lane] : -INFINITY;
    float mx = fmaxf(x0, x1);
#pragma unroll
    for (int off = 32; off; off >>= 1) mx = fmaxf(mx, __shfl_xor(mx, off, 64));
    float e0 = expf(x0 - mx);
    float e1 = (lane < 16) ? expf(x1 - mx) : 0.f;
    float ssum = wave_red_sum(e0 + e1);
    p[lane] = e0 / ssum;
    if (lane < 16) p[64 + lane] = e1 / ssum;
  }
  __syncthreads();
  float acc[5] = {0, 0, 0, 0, 0};
  for (int m2 = 0; m2 < 80; ++m2) {
    float pm = p[m2];
    const float* vrow = qkv + (size_t)(b * NBOU + m2) * OQKV + 2 * DTOK;
#pragma unroll
    for (int i = 0; i < 5; ++i) {
      int d = tid + 256 * i;
      if (d < DTOK) acc[i] += pm * vrow[d];
    }
  }
#pragma unroll
  for (int i = 0; i < 5; ++i) {
    int d = tid + 256 * i;
    if (d < DTOK) attn_out[(size_t)blk * DTOK + d] = acc[i];
  }
}

// ---------- LayerNorm ----------
__global__ __launch_bounds__(256) void k_ln(const float* __restrict__ xin,
                                            const float* __restrict__ g,
                                            const float* __restrict__ bb,
                                            float* __restrict__ xout) {
  int m = blockIdx.x, tid = threadIdx.x;
  __shared__ float row[DTOK];
  __shared__ float rb[8];
  const float* xr = xin + (size_t)m * DTOK;
  float ls = 0.f;
  for (int d = tid; d < DTOK; d += 256) { float v = xr[d]; row[d] = v; ls += v; }
  float mean = block_red_sum(ls, rb, tid) * (1.0f / DTOK);
  float lq = 0.f;
  for (int d = tid; d < DTOK; d += 256) { float t = row[d] - mean; lq += t * t; }
  float var = block_red_sum(lq, rb, tid) * (1.0f / DTOK);
  float rstd = rsqrtf(var + 1e-5f);
  for (int d = tid; d < DTOK; d += 256)
    xout[(size_t)m * DTOK + d] = (row[d] - mean) * rstd * g[d] + bb[d];
}

// ---------- fc head (only outputs 0,1) + boundary update ----------
__global__ __launch_bounds__(256) void k_fc(const float* __restrict__ x2,
                                            const float* __restrict__ fcw,
                                            const float* __restrict__ fcb,
                                            int* __restrict__ bnd,
                                            int* __restrict__ outp) {
  int blk = blockIdx.x;
  int n = blk % NBOU;
  int tid = threadIdx.x;
  __shared__ float rb[8];
  const float* xr = x2 + (size_t)blk * DTOK;
  const float* w0 = fcw + (size_t)n * 1026 * DTOK;
  const float* w1 = w0 + DTOK;
  float s0 = 0.f, s1 = 0.f;
  for (int d = tid; d < DTOK; d += 256) {
    float x = xr[d];
    s0 += x * w0[d];
    s1 += x * w1[d];
  }
  s0 = block_red_sum(s0, rb, tid);
  s1 = block_red_sum(s1, rb, tid);
  if (tid == 0) {
    float o0 = s0 + fcb[n * 1026 + 0];
    float o1 = s1 + fcb[n * 1026 + 1];
    int b0 = bnd[blk * 2 + 0], b1 = bnd[blk * 2 + 1];
    int nb0 = b0 + (int)truncf(o0);
    int nb1 = b1 + (int)truncf(o1);
    nb0 = nb0 < 0 ? 0 : (nb0 > 223 ? 223 : nb0);
    nb1 = nb1 < 0 ? 0 : (nb1 > 223 ? 223 : nb1);
    bnd[blk * 2 + 0] = nb0;
    bnd[blk * 2 + 1] = nb1;
    outp[blk * 2 + 0] = nb0;
    outp[blk * 2 + 1] = nb1;
  }
}

extern "C" void kernel_launch(void* const* d_in, const int* in_sizes, int n_in,
                              void* d_out, int out_size, void* d_ws, size_t ws_size,
                              hipStream_t stream) {
  const float* f   = (const float*)d_in[0];
  const int*   pb  = (const int*)d_in[1];
  const float* lng = (const float*)d_in[2];
  const float* lnb = (const float*)d_in[3];
  const float* ipw = (const float*)d_in[4];
  const float* ipb = (const float*)d_in[5];
  const float* opw = (const float*)d_in[6];
  const float* opb = (const float*)d_in[7];
  const float* l1w = (const float*)d_in[8];
  const float* l1b = (const float*)d_in[9];
  const float* l2w = (const float*)d_in[10];
  const float* l2b = (const float*)d_in[11];
  const float* n1g = (const float*)d_in[12];
  const float* n1b = (const float*)d_in[13];
  const float* n2g = (const float*)d_in[14];
  const float* n2b = (const float*)d_in[15];
  const float* fcw = (const float*)d_in[16];
  const float* fcb = (const float*)d_in[17];
  int* outp = (int*)d_out;

  float* ws = (float*)d_ws;
  float* L1 = ws;                                        // 2*112*112*1024
  float* L2 = L1 + (size_t)2 * 112 * 112 * 1024;         // 2*56*56*1024
  float* L3 = L2 + (size_t)2 * 56 * 56 * 1024;           // 2*28*28*1024
  float* pe = L3 + (size_t)2 * 28 * 28 * 1024;           // 80*1222
  int* bnd = (int*)(pe + (size_t)NBOU * DTOK);           // 320 ints
  float* tokens = (float*)(bnd + 320);
  float* qkvb   = tokens + (size_t)MM * DTOK;
  float* attnb  = qkvb + (size_t)MM * OQKV;
  float* x1pre  = attnb + (size_t)MM * DTOK;
  float* x1     = x1pre + (size_t)MM * DTOK;
  float* hb     = x1 + (size_t)MM * DTOK;
  float* x2pre  = hb + (size_t)MM * FFD;
  float* x2     = x2pre + (size_t)MM * DTOK;

  k_pool0<<<dim3(64, 112, 2), 256, 0, stream>>>(f, L1);
  k_pool_nhwc<<<dim3(56, 56, 2), 256, 0, stream>>>(L1, L2, 56);
  k_pool_nhwc<<<dim3(28, 28, 2), 256, 0, stream>>>(L2, L3, 28);
  k_pe<<<NBOU, 256, 0, stream>>>(pe, bnd, pb);

  for (int it = 0; it < 6; ++it) {
    k_tok<<<160, 256, 0, stream>>>(f, L1, L2, L3, bnd, lng, lnb, pe, tokens);
    k_gemm<<<dim3(58, 3), 256, 0, stream>>>(tokens, ipw, ipb, nullptr, qkvb, DTOK, OQKV, 0);
    k_attn<<<160, 256, 0, stream>>>(qkvb, attnb);
    k_gemm<<<dim3(20, 3), 256, 0, stream>>>(attnb, opw, opb, tokens, x1pre, DTOK, DTOK, 0);
    k_ln<<<160, 256, 0, stream>>>(x1pre, n1g, n1b, x1);
    k_gemm<<<dim3(32, 3), 256, 0, stream>>>(x1, l1w, l1b, nullptr, hb, DTOK, FFD, 1);
    k_gemm<<<dim3(20, 3), 256, 0, stream>>>(hb, l2w, l2b, x1, x2pre, FFD, DTOK, 0);
    k_ln<<<160, 256, 0, stream>>>(x2pre, n2g, n2b, x2);
    k_fc<<<160, 256, 0, stream>>>(x2, fcw, fcb, bnd, outp + it * 320);
  }
}

// Round 3
// 2653.853 us; speedup vs baseline: 2.9641x; 2.9641x over previous
//
#include <hip/hip_runtime.h>
#include <math.h>

#define DTOK 1222
#define NBOU 80
#define MM   160
#define FFD  2048
#define OQKV 3666

// ---------- reduction helpers (block = 256 threads = 4 waves) ----------
__device__ __forceinline__ float wave_red_sum(float v) {
#pragma unroll
  for (int off = 32; off; off >>= 1) v += __shfl_xor(v, off, 64);
  return v;
}

__device__ __forceinline__ float block_red_sum(float v, float* rb, int tid) {
  v = wave_red_sum(v);
  __syncthreads();
  if ((tid & 63) == 0) rb[tid >> 6] = v;
  __syncthreads();
  return rb[0] + rb[1] + rb[2] + rb[3];
}

// ---------- setup: pool L0 (NCHW) -> L1 (NHWC) ----------
__global__ __launch_bounds__(256) void k_pool0(const float* __restrict__ f,
                                               float* __restrict__ L1out) {
  int xc = blockIdx.x & 3, cc = blockIdx.x >> 2;
  int y1 = blockIdx.y, b = blockIdx.z;
  int tid = threadIdx.x;
  __shared__ __align__(16) float tile[64][116];
  int c0 = cc * 64, x0 = xc * 56;
  const float* fb = f + (size_t)b * 1024 * 50176;
#pragma unroll
  for (int i = 0; i < 7; ++i) {
    int u = tid + 256 * i;
    int q = u % 14;
    int seg = u / 14;
    int c = seg >> 1, r = seg & 1;
    const float* src = fb + ((size_t)(c0 + c) * 224 + (2 * y1 + r)) * 224 + x0 + q * 4;
    float4 v = *(const float4*)src;
    *(float4*)&tile[c][r * 56 + q * 4] = v;
  }
  __syncthreads();
#pragma unroll
  for (int i = 0; i < 7; ++i) {
    int u = tid + 256 * i;
    int xo = u >> 6;
    int c = u & 63;
    float v = 0.25f * (tile[c][2 * xo] + tile[c][2 * xo + 1] +
                       tile[c][56 + 2 * xo] + tile[c][56 + 2 * xo + 1]);
    L1out[(((size_t)b * 112 + y1) * 112 + (x0 >> 1) + xo) * 1024 + c0 + c] = v;
  }
}

// ---------- setup: pool NHWC -> NHWC (2x2 mean) ----------
__global__ __launch_bounds__(256) void k_pool_nhwc(const float* __restrict__ in,
                                                   float* __restrict__ out, int Ho) {
  int x = blockIdx.x, y = blockIdx.y, b = blockIdx.z;
  int c = threadIdx.x * 4;
  int Hi = Ho * 2;
  const float* p00 = in + (((size_t)(b * Hi + 2 * y) * Hi) + 2 * x) * 1024 + c;
  const float* p01 = p00 + 1024;
  const float* p10 = p00 + (size_t)Hi * 1024;
  const float* p11 = p10 + 1024;
  float4 a = *(const float4*)p00, bv = *(const float4*)p01;
  float4 cv = *(const float4*)p10, dv = *(const float4*)p11;
  float4 r;
  r.x = 0.25f * (a.x + bv.x + cv.x + dv.x);
  r.y = 0.25f * (a.y + bv.y + cv.y + dv.y);
  r.z = 0.25f * (a.z + bv.z + cv.z + dv.z);
  r.w = 0.25f * (a.w + bv.w + cv.w + dv.w);
  *(float4*)(out + (((size_t)(b * Ho + y) * Ho) + x) * 1024 + c) = r;
}

// ---------- setup: positional encoding + boundary init ----------
__global__ __launch_bounds__(256) void k_pe(float* __restrict__ pe, int* __restrict__ bnd,
                                            const int* __restrict__ pb) {
  int n = blockIdx.x, tid = threadIdx.x;
  for (int d = tid; d < DTOK; d += 256) {
    int i = d >> 1;
    double e = exp((double)(2 * i) * (-log(10000.0) / (double)DTOK));
    double ang = (double)n * e;
    pe[n * DTOK + d] = (float)((d & 1) ? cos(ang) : sin(ang));
  }
  if (n == 0) {
    for (int t = tid; t < 2 * NBOU * 2; t += 256) bnd[t] = pb[t];
  }
}

// ---------- per-iteration: gather + dots + tokens + LN + pe ----------
__global__ __launch_bounds__(256) void k_tok(const float* __restrict__ f,
                                             const float* __restrict__ L1,
                                             const float* __restrict__ L2,
                                             const float* __restrict__ L3,
                                             const int* __restrict__ bnd,
                                             const float* __restrict__ g,
                                             const float* __restrict__ bb,
                                             const float* __restrict__ pe,
                                             float* __restrict__ tok_out) {
  int blk = blockIdx.x;
  int b = blk / NBOU, n = blk % NBOU;
  int tid = threadIdx.x, wave = tid >> 6, lane = tid & 63;
  __shared__ __align__(16) float token[1224];
  __shared__ float red[4][52];
  __shared__ float rbuf[8];
  int bd0 = bnd[blk * 2 + 0], bd1 = bnd[blk * 2 + 1];

  int oh = lane / 7 - 3, ow = lane % 7 - 3;
  int py = bd0 + oh, px = bd1 + ow;
  bool valid = (lane < 49) && (py >= 0) && (py < 224) && (px >= 0) && (px < 224);
  const float* fb = f + (size_t)b * 1024 * 50176;
  long sp = (long)py * 224 + px;
  float acc0 = 0.f;
  int c0 = wave * 256;
#pragma unroll 8
  for (int c = 0; c < 256; ++c) {
    int ch = c0 + c;
    float v = valid ? fb[(size_t)ch * 50176 + sp] : 0.f;
    float qc = __shfl(v, 24, 64);
    acc0 += qc * v;
    if (lane == 24) token[ch] = v;
  }
  if (lane < 49) red[wave][lane] = acc0;
  __syncthreads();
  if (tid < 49) token[1024 + tid] = red[0][tid] + red[1][tid] + red[2][tid] + red[3][tid];
  if (tid == 0) { token[1220] = (float)bd0; token[1221] = (float)bd1; }
  __syncthreads();

#pragma unroll
  for (int s = 1; s <= 3; ++s) {
    const float* base = (s == 1) ? L1 : (s == 2) ? L2 : L3;
    int Hs = 224 >> s;
    int by = bd0 >> s, bx = bd1 >> s;
    const float* bp = base + (size_t)b * Hs * Hs * 1024;
    for (int o = wave; o < 49; o += 4) {
      int yy = by + o / 7 - 3, xx = bx + o % 7 - 3;
      float a = 0.f;
      if (yy >= 0 && yy < Hs && xx >= 0 && xx < Hs) {
        const float* kp = bp + ((size_t)yy * Hs + xx) * 1024;
#pragma unroll
        for (int j = 0; j < 4; ++j) {
          int c = (lane + 64 * j) * 4;
          float4 kv = *(const float4*)(kp + c);
          float4 qv = *(const float4*)(token + c);
          a += kv.x * qv.x + kv.y * qv.y + kv.z * qv.z + kv.w * qv.w;
        }
      }
      a = wave_red_sum(a);
      if (lane == 0) token[1024 + s * 49 + o] = a;
    }
  }
  __syncthreads();

  float ls = 0.f;
  for (int d = tid; d < DTOK; d += 256) ls += token[d];
  float mean = block_red_sum(ls, rbuf, tid) * (1.0f / DTOK);
  float lq = 0.f;
  for (int d = tid; d < DTOK; d += 256) { float t = token[d] - mean; lq += t * t; }
  float var = block_red_sum(lq, rbuf, tid) * (1.0f / DTOK);
  float rstd = rsqrtf(var + 1e-5f);
  for (int d = tid; d < DTOK; d += 256) {
    float o = (token[d] - mean) * rstd * g[d] + bb[d] + pe[n * DTOK + d];
    tok_out[(size_t)blk * DTOK + d] = o;
  }
}

// ---------- split-K fp32 GEMM: partial[sp] = A[160,K(c0:c1)] @ W[O,K]^T ----------
// grid (ceil(O/64), 3, S); 64x64 tile; register-prefetch double buffering.
__global__ __launch_bounds__(256) void k_gemm2(const float* __restrict__ A,
                                               const float* __restrict__ Wt,
                                               float* __restrict__ partial,
                                               int K, int O, int S) {
  __shared__ __align__(16) float At[32][68];
  __shared__ __align__(16) float Bt[32][68];
  int tid = threadIdx.x;
  int o0 = blockIdx.x * 64, m0 = blockIdx.y * 64, sp = blockIdx.z;
  int chunks = (K + 31) >> 5;
  int cps = (chunks + S - 1) / S;
  int c0 = sp * cps, c1 = min(c0 + cps, chunks);

  int kk = tid & 31, rr = tid >> 5;
  int tm = tid & 15, to = tid >> 4;
  float acc[4][4] = {};

  if (c0 < c1) {
    float ra[8], rb[8];
    // prologue load chunk c0
    {
      int kg = c0 * 32 + kk;
      bool kval = kg < K;
#pragma unroll
      for (int i = 0; i < 8; ++i) {
        int row = rr + 8 * i;
        int m = m0 + row, o = o0 + row;
        ra[i] = (kval && m < MM) ? A[(size_t)m * K + kg] : 0.f;
        rb[i] = (kval && o < O) ? Wt[(size_t)o * K + kg] : 0.f;
      }
    }
    for (int c = c0; c < c1; ++c) {
      __syncthreads();
#pragma unroll
      for (int i = 0; i < 8; ++i) {
        int row = rr + 8 * i;
        At[kk][row] = ra[i];
        Bt[kk][row] = rb[i];
      }
      __syncthreads();
      if (c + 1 < c1) {                 // prefetch next chunk into regs
        int kg = (c + 1) * 32 + kk;
        bool kval = kg < K;
#pragma unroll
        for (int i = 0; i < 8; ++i) {
          int row = rr + 8 * i;
          int m = m0 + row, o = o0 + row;
          ra[i] = (kval && m < MM) ? A[(size_t)m * K + kg] : 0.f;
          rb[i] = (kval && o < O) ? Wt[(size_t)o * K + kg] : 0.f;
        }
      }
#pragma unroll
      for (int q = 0; q < 32; ++q) {
        float4 av = *(const float4*)&At[q][tm * 4];
        float4 bv = *(const float4*)&Bt[q][to * 4];
        float a4[4] = {av.x, av.y, av.z, av.w};
        float b4[4] = {bv.x, bv.y, bv.z, bv.w};
#pragma unroll
        for (int im = 0; im < 4; ++im)
#pragma unroll
          for (int io = 0; io < 4; ++io) acc[im][io] += a4[im] * b4[io];
      }
    }
  }
  // write partial (zeros if this split had no chunks)
#pragma unroll
  for (int im = 0; im < 4; ++im) {
    int m = m0 + tm * 4 + im;
    if (m >= MM) continue;
#pragma unroll
    for (int io = 0; io < 4; ++io) {
      int o = o0 + to * 4 + io;
      if (o < O) partial[((size_t)sp * MM + m) * O + o] = acc[im][io];
    }
  }
}

// ---------- split-K reduce + bias (+relu)(+res) ----------
__global__ __launch_bounds__(256) void k_red(const float* __restrict__ partial,
                                             const float* __restrict__ bias,
                                             const float* __restrict__ res,
                                             float* __restrict__ out,
                                             int O, int S, int relu) {
  size_t idx = ((size_t)blockIdx.x * 256 + threadIdx.x) * 4;
  size_t total = (size_t)MM * O;
  if (idx >= total) return;
  float4 v = *(const float4*)(partial + idx);
  for (int s = 1; s < S; ++s) {
    float4 p = *(const float4*)(partial + (size_t)s * total + idx);
    v.x += p.x; v.y += p.y; v.z += p.z; v.w += p.w;
  }
  float r[4] = {v.x, v.y, v.z, v.w};
#pragma unroll
  for (int j = 0; j < 4; ++j) {
    int o = (int)((idx + j) % O);
    r[j] += bias[o];
    if (relu) r[j] = fmaxf(r[j], 0.f);
  }
  if (res) {
    float4 q = *(const float4*)(res + idx);
    r[0] += q.x; r[1] += q.y; r[2] += q.z; r[3] += q.w;
  }
  float4 w = {r[0], r[1], r[2], r[3]};
  *(float4*)(out + idx) = w;
}

// ---------- attention (per (b,n) row) ----------
__global__ __launch_bounds__(256) void k_attn(const float* __restrict__ qkv,
                                              float* __restrict__ attn_out) {
  int blk = blockIdx.x;
  int b = blk / NBOU;
  int tid = threadIdx.x, wave = tid >> 6, lane = tid & 63;
  __shared__ float p[80];
  float qr[20];
  const float* qrow = qkv + (size_t)blk * OQKV;
#pragma unroll
  for (int j = 0; j < 20; ++j) {
    int d = lane + 64 * j;
    qr[j] = (d < DTOK) ? qrow[d] : 0.f;
  }
  for (int m2 = wave; m2 < 80; m2 += 4) {
    const float* krow = qkv + (size_t)(b * NBOU + m2) * OQKV + DTOK;
    float a = 0.f;
#pragma unroll
    for (int j = 0; j < 20; ++j) {
      int d = lane + 64 * j;
      if (d < DTOK) a += qr[j] * krow[d];
    }
    a = wave_red_sum(a);
    if (lane == 0) p[m2] = a * (1.0f / 34.957116f);
  }
  __syncthreads();
  if (wave == 0) {
    float x0 = p[lane];
    float x1 = (lane < 16) ? p[64 + lane] : -INFINITY;
    float mx = fmaxf(x0, x1);
#pragma unroll
    for (int off = 32; off; off >>= 1) mx = fmaxf(mx, __shfl_xor(mx, off, 64));
    float e0 = expf(x0 - mx);
    float e1 = (lane < 16) ? expf(x1 - mx) : 0.f;
    float ssum = wave_red_sum(e0 + e1);
    p[lane] = e0 / ssum;
    if (lane < 16) p[64 + lane] = e1 / ssum;
  }
  __syncthreads();
  float acc[5] = {0, 0, 0, 0, 0};
  for (int m2 = 0; m2 < 80; ++m2) {
    float pm = p[m2];
    const float* vrow = qkv + (size_t)(b * NBOU + m2) * OQKV + 2 * DTOK;
#pragma unroll
    for (int i = 0; i < 5; ++i) {
      int d = tid + 256 * i;
      if (d < DTOK) acc[i] += pm * vrow[d];
    }
  }
#pragma unroll
  for (int i = 0; i < 5; ++i) {
    int d = tid + 256 * i;
    if (d < DTOK) attn_out[(size_t)blk * DTOK + d] = acc[i];
  }
}

// ---------- LayerNorm ----------
__global__ __launch_bounds__(256) void k_ln(const float* __restrict__ xin,
                                            const float* __restrict__ g,
                                            const float* __restrict__ bb,
                                            float* __restrict__ xout) {
  int m = blockIdx.x, tid = threadIdx.x;
  __shared__ float row[DTOK];
  __shared__ float rb[8];
  const float* xr = xin + (size_t)m * DTOK;
  float ls = 0.f;
  for (int d = tid; d < DTOK; d += 256) { float v = xr[d]; row[d] = v; ls += v; }
  float mean = block_red_sum(ls, rb, tid) * (1.0f / DTOK);
  float lq = 0.f;
  for (int d = tid; d < DTOK; d += 256) { float t = row[d] - mean; lq += t * t; }
  float var = block_red_sum(lq, rb, tid) * (1.0f / DTOK);
  float rstd = rsqrtf(var + 1e-5f);
  for (int d = tid; d < DTOK; d += 256)
    xout[(size_t)m * DTOK + d] = (row[d] - mean) * rstd * g[d] + bb[d];
}

// ---------- fc head (only outputs 0,1) + boundary update ----------
__global__ __launch_bounds__(256) void k_fc(const float* __restrict__ x2,
                                            const float* __restrict__ fcw,
                                            const float* __restrict__ fcb,
                                            int* __restrict__ bnd,
                                            int* __restrict__ outp) {
  int blk = blockIdx.x;
  int n = blk % NBOU;
  int tid = threadIdx.x;
  __shared__ float rb[8];
  const float* xr = x2 + (size_t)blk * DTOK;
  const float* w0 = fcw + (size_t)n * 1026 * DTOK;
  const float* w1 = w0 + DTOK;
  float s0 = 0.f, s1 = 0.f;
  for (int d = tid; d < DTOK; d += 256) {
    float x = xr[d];
    s0 += x * w0[d];
    s1 += x * w1[d];
  }
  s0 = block_red_sum(s0, rb, tid);
  s1 = block_red_sum(s1, rb, tid);
  if (tid == 0) {
    float o0 = s0 + fcb[n * 1026 + 0];
    float o1 = s1 + fcb[n * 1026 + 1];
    int b0 = bnd[blk * 2 + 0], b1 = bnd[blk * 2 + 1];
    int nb0 = b0 + (int)truncf(o0);
    int nb1 = b1 + (int)truncf(o1);
    nb0 = nb0 < 0 ? 0 : (nb0 > 223 ? 223 : nb0);
    nb1 = nb1 < 0 ? 0 : (nb1 > 223 ? 223 : nb1);
    bnd[blk * 2 + 0] = nb0;
    bnd[blk * 2 + 1] = nb1;
    outp[blk * 2 + 0] = nb0;
    outp[blk * 2 + 1] = nb1;
  }
}

extern "C" void kernel_launch(void* const* d_in, const int* in_sizes, int n_in,
                              void* d_out, int out_size, void* d_ws, size_t ws_size,
                              hipStream_t stream) {
  const float* f   = (const float*)d_in[0];
  const int*   pb  = (const int*)d_in[1];
  const float* lng = (const float*)d_in[2];
  const float* lnb = (const float*)d_in[3];
  const float* ipw = (const float*)d_in[4];
  const float* ipb = (const float*)d_in[5];
  const float* opw = (const float*)d_in[6];
  const float* opb = (const float*)d_in[7];
  const float* l1w = (const float*)d_in[8];
  const float* l1b = (const float*)d_in[9];
  const float* l2w = (const float*)d_in[10];
  const float* l2b = (const float*)d_in[11];
  const float* n1g = (const float*)d_in[12];
  const float* n1b = (const float*)d_in[13];
  const float* n2g = (const float*)d_in[14];
  const float* n2b = (const float*)d_in[15];
  const float* fcw = (const float*)d_in[16];
  const float* fcb = (const float*)d_in[17];
  int* outp = (int*)d_out;

  float* ws = (float*)d_ws;
  float* L1 = ws;                                        // 2*112*112*1024
  float* L2 = L1 + (size_t)2 * 112 * 112 * 1024;         // 2*56*56*1024
  float* L3 = L2 + (size_t)2 * 56 * 56 * 1024;           // 2*28*28*1024
  float* pe = L3 + (size_t)2 * 28 * 28 * 1024;           // 80*1222
  int* bnd = (int*)(pe + (size_t)NBOU * DTOK);           // 320 ints
  float* tokens = (float*)(bnd + 320);
  float* qkvb   = tokens + (size_t)MM * DTOK;
  float* attnb  = qkvb + (size_t)MM * OQKV;
  float* x1pre  = attnb + (size_t)MM * DTOK;
  float* x1     = x1pre + (size_t)MM * DTOK;
  float* hb     = x1 + (size_t)MM * DTOK;
  float* x2pre  = hb + (size_t)MM * FFD;
  float* x2     = x2pre + (size_t)MM * DTOK;
  float* part   = x2 + (size_t)MM * DTOK;                // up to 4*160*3666 floats

  k_pool0<<<dim3(64, 112, 2), 256, 0, stream>>>(f, L1);
  k_pool_nhwc<<<dim3(56, 56, 2), 256, 0, stream>>>(L1, L2, 56);
  k_pool_nhwc<<<dim3(28, 28, 2), 256, 0, stream>>>(L2, L3, 28);
  k_pe<<<NBOU, 256, 0, stream>>>(pe, bnd, pb);

  for (int it = 0; it < 6; ++it) {
    k_tok<<<160, 256, 0, stream>>>(f, L1, L2, L3, bnd, lng, lnb, pe, tokens);

    // in_proj: [160,1222] @ [3666,1222]^T, split-K=4
    k_gemm2<<<dim3(58, 3, 4), 256, 0, stream>>>(tokens, ipw, part, DTOK, OQKV, 4);
    k_red<<<573, 256, 0, stream>>>(part, ipb, nullptr, qkvb, OQKV, 4, 0);

    k_attn<<<160, 256, 0, stream>>>(qkvb, attnb);

    // out_proj: [160,1222] @ [1222,1222]^T + tokens, split-K=6
    k_gemm2<<<dim3(20, 3, 6), 256, 0, stream>>>(attnb, opw, part, DTOK, DTOK, 6);
    k_red<<<191, 256, 0, stream>>>(part, opb, tokens, x1pre, DTOK, 6, 0);

    k_ln<<<160, 256, 0, stream>>>(x1pre, n1g, n1b, x1);

    // lin1: [160,1222] @ [2048,1222]^T, relu, split-K=6
    k_gemm2<<<dim3(32, 3, 6), 256, 0, stream>>>(x1, l1w, part, DTOK, FFD, 6);
    k_red<<<320, 256, 0, stream>>>(part, l1b, nullptr, hb, FFD, 6, 1);

    // lin2: [160,2048] @ [1222,2048]^T + x1, split-K=6
    k_gemm2<<<dim3(20, 3, 6), 256, 0, stream>>>(hb, l2w, part, FFD, DTOK, 6);
    k_red<<<191, 256, 0, stream>>>(part, l2b, x1, x2pre, DTOK, 6, 0);

    k_ln<<<160, 256, 0, stream>>>(x2pre, n2g, n2b, x2);
    k_fc<<<160, 256, 0, stream>>>(x2, fcw, fcb, bnd, outp + it * 320);
  }
}